// Round 2
// baseline (430.798 us; speedup 1.0000x reference)
//
#include <hip/hip_runtime.h>
#include <math.h>

#define Bn 8
#define Hn 128
#define Pn 128
#define Ln 4096
#define LF 2049           // Ln/2 + 1
#define NROWS (Bn*Hn)     // 1024
#define TL 4              // l-bins per mixfreq block

// ---------------------------------------------------------------------------
// prep kernels: fold the H-axis FFTs into the weight matrices.
//   B2t[h][p] = (B_bar @ F)[p][h]
//   C2t[p][h] = (Finv @ C)[h][p]
//   E[a][q]   = (D @ F)[a][q]     (temp)
//   D2t[q][h] = (Finv @ E)[h][q]
// ---------------------------------------------------------------------------

__global__ void prep_B2t_k(const float* __restrict__ B_ri, float2* __restrict__ B2t) {
    int idx = blockIdx.x * blockDim.x + threadIdx.x;   // h*128 + p
    int h = idx >> 7, p = idx & 127;
    float sr = 0.f, si = 0.f;
    for (int q = 0; q < 128; ++q) {
        float br = B_ri[(p * 128 + q) * 2 + 0];
        float bi = B_ri[(p * 128 + q) * 2 + 1];
        float ang = -3.14159265358979f * (float)((q * h) & 127) / 64.0f;
        float sw, cw; __sincosf(ang, &sw, &cw);
        sr += br * cw - bi * sw;
        si += br * sw + bi * cw;
    }
    B2t[idx] = make_float2(sr, si);
}

__global__ void prep_C2t_k(const float* __restrict__ C_ri, float2* __restrict__ C2t) {
    int idx = blockIdx.x * blockDim.x + threadIdx.x;   // p*128 + h
    int p = idx >> 7, h = idx & 127;
    float sr = 0.f, si = 0.f;
    for (int h2 = 0; h2 < 128; ++h2) {
        float cr = C_ri[(h2 * 128 + p) * 2 + 0];
        float ci = C_ri[(h2 * 128 + p) * 2 + 1];
        float ang = 3.14159265358979f * (float)((h * h2) & 127) / 64.0f;
        float sw, cw; __sincosf(ang, &sw, &cw);
        sr += cr * cw - ci * sw;
        si += cr * sw + ci * cw;
    }
    C2t[idx] = make_float2(sr * (1.0f / 128.0f), si * (1.0f / 128.0f));
}

__global__ void prep_E_k(const float* __restrict__ D_ri, float2* __restrict__ E) {
    int idx = blockIdx.x * blockDim.x + threadIdx.x;   // a*128 + q
    int a = idx >> 7, q = idx & 127;
    float sr = 0.f, si = 0.f;
    for (int c = 0; c < 128; ++c) {
        float dr = D_ri[(a * 128 + c) * 2 + 0];
        float di = D_ri[(a * 128 + c) * 2 + 1];
        float ang = -3.14159265358979f * (float)((c * q) & 127) / 64.0f;
        float sw, cw; __sincosf(ang, &sw, &cw);
        sr += dr * cw - di * sw;
        si += dr * sw + di * cw;
    }
    E[idx] = make_float2(sr, si);
}

__global__ void prep_D2t_k(const float2* __restrict__ E, float2* __restrict__ D2t) {
    int idx = blockIdx.x * blockDim.x + threadIdx.x;   // q*128 + h
    int q = idx >> 7, h = idx & 127;
    float sr = 0.f, si = 0.f;
    for (int a = 0; a < 128; ++a) {
        float2 e = E[a * 128 + q];
        float ang = 3.14159265358979f * (float)((h * a) & 127) / 64.0f;
        float sw, cw; __sincosf(ang, &sw, &cw);
        sr += e.x * cw - e.y * sw;
        si += e.x * sw + e.y * cw;
    }
    D2t[idx] = make_float2(sr * (1.0f / 128.0f), si * (1.0f / 128.0f));
}

// ---------------------------------------------------------------------------
// 4096-pt Stockham radix-4 FFT in LDS. SIGN=-1 forward, +1 inverse
// (unnormalized). 256 threads, 4 radix-4 butterflies/thread/stage, 6 stages.
// Derived by composing two radix-2 Stockham stages:
//   dst[q+(4p+j)s] = (sum_u a_u e^{SIGN*2pi*i*j*u/4}) * e^{SIGN*2pi*i*j*p/n}
// Result ends in bufA. Caller syncs after filling bufA.
// ---------------------------------------------------------------------------
template <int SIGN>
__device__ __forceinline__ void stockham4096_r4(float2* bufA, float2* bufB) {
    const int tid = threadIdx.x;
    float2* src = bufA;
    float2* dst = bufB;
    #pragma unroll
    for (int st = 0; st < 6; ++st) {
        const int ls = 2 * st;            // log2(s), s = 4^st
        const int n = 4096 >> ls;         // transform length this stage
        const int mq = n >> 2;            // n/4
        const float invn = 1.0f / (float)n;
        #pragma unroll
        for (int r = 0; r < 4; ++r) {
            int k = tid + (r << 8);       // 0..1023
            int q = k & ((1 << ls) - 1);
            int p = k >> ls;              // < mq
            float2 a0 = src[q + ((p         ) << ls)];
            float2 a1 = src[q + ((p +     mq) << ls)];
            float2 a2 = src[q + ((p + 2 * mq) << ls)];
            float2 a3 = src[q + ((p + 3 * mq) << ls)];
            float t0x = a0.x + a2.x, t0y = a0.y + a2.y;
            float t1x = a0.x - a2.x, t1y = a0.y - a2.y;
            float t2x = a1.x + a3.x, t2y = a1.y + a3.y;
            float t3x = a1.x - a3.x, t3y = a1.y - a3.y;
            float B0x = t0x + t2x, B0y = t0y + t2y;
            float B2x = t0x - t2x, B2y = t0y - t2y;
            float B1x = t1x - (float)SIGN * t3y, B1y = t1y + (float)SIGN * t3x;
            float B3x = t1x + (float)SIGN * t3y, B3y = t1y - (float)SIGN * t3x;
            float ang = (float)SIGN * 6.28318530717959f * (float)p * invn;
            float s1, c1; __sincosf(ang, &s1, &c1);
            float c2 = c1 * c1 - s1 * s1, s2 = 2.0f * c1 * s1;
            float c3 = c2 * c1 - s2 * s1, s3 = c2 * s1 + s2 * c1;
            int o = q + (p << (ls + 2));
            dst[o              ] = make_float2(B0x, B0y);
            dst[o + (1 << ls)  ] = make_float2(B1x * c1 - B1y * s1, B1x * s1 + B1y * c1);
            dst[o + (2 << ls)  ] = make_float2(B2x * c2 - B2y * s2, B2x * s2 + B2y * c2);
            dst[o + (3 << ls)  ] = make_float2(B3x * c3 - B3y * s3, B3x * s3 + B3y * c3);
        }
        __syncthreads();
        float2* t = src; src = dst; dst = t;
    }
    // 6 swaps -> result back in bufA
}

__global__ __launch_bounds__(256) void rfft_rows_k(const float* __restrict__ u,
                                                   float2* __restrict__ Uhat) {
    __shared__ __align__(16) float2 bufA[4096];
    __shared__ __align__(16) float2 bufB[4096];
    const int row = blockIdx.x;
    const int tid = threadIdx.x;
    const float* up = u + (size_t)row * Ln;
    for (int i = tid; i < Ln; i += 256) bufA[i] = make_float2(up[i], 0.f);
    __syncthreads();
    stockham4096_r4<-1>(bufA, bufB);
    float2* op = Uhat + (size_t)row * LF;
    for (int l = tid; l < LF; l += 256) op[l] = bufA[l];
}

__global__ __launch_bounds__(256) void irfft_gelu_k(const float2* __restrict__ Uhat,
                                                    float* __restrict__ out) {
    __shared__ __align__(16) float2 bufA[4096];
    __shared__ __align__(16) float2 bufB[4096];
    const int row = blockIdx.x;
    const int tid = threadIdx.x;
    const float2* wp = Uhat + (size_t)row * LF;
    for (int l = tid; l < LF; l += 256) {
        float2 v = wp[l];
        bufA[l] = v;
        if (l >= 1 && l <= Ln / 2 - 1) bufA[Ln - l] = make_float2(v.x, -v.y);
    }
    __syncthreads();
    stockham4096_r4<1>(bufA, bufB);
    float* op = out + (size_t)row * Ln;
    for (int i = tid; i < Ln; i += 256) {
        float y = bufA[i].x * (1.0f / (float)Ln);
        op[i] = 0.5f * y * (1.0f + erff(y * 0.70710678118655f));
    }
}

// ---------------------------------------------------------------------------
// mixfreq: per frequency bin l:
//   W[b,:,l] = C2 * diag(mid(:,l)) * B2 * U[b,:,l] + D2 * U[b,:,l]
// In-place on Uhat. One block = TL=4 consecutive bins, all (b,h).
// Restructured: bins innermost in registers (acc[4 rows][4 bins]) so each
// weight load feeds 64 FMAs and LDS rows are read as b128 broadcasts.
// 4 barriers total. LDS exactly 64 KB -> 2 blocks/CU.
// ---------------------------------------------------------------------------
__global__ __launch_bounds__(256) void mixfreq_k(float2* __restrict__ Uhat,
                                                 const float2* __restrict__ B2t,
                                                 const float2* __restrict__ C2t,
                                                 const float2* __restrict__ D2t,
                                                 const float* __restrict__ Lam) {
    __shared__ __align__(16) float2 Us[NROWS][TL];   // 32 KB
    __shared__ __align__(16) float2 Tm[NROWS][TL];   // 32 KB
    const int tid = threadIdx.x;
    const int l0 = blockIdx.x * TL;

    for (int i = tid; i < NROWS * TL; i += 256) {
        int r = i >> 2, j = i & (TL - 1);
        int l = l0 + j;
        Us[r][j] = (l < LF) ? Uhat[(size_t)r * LF + l] : make_float2(0.f, 0.f);
    }
    __syncthreads();

    const int pp = tid & 127;   // p (phase 1) / h (phase 2)
    const int b0 = tid >> 7;    // rows b = b0 + 2r, r = 0..3

    float2 acc[4][4];
    #pragma unroll
    for (int r = 0; r < 4; ++r)
        #pragma unroll
        for (int j = 0; j < 4; ++j) acc[r][j] = make_float2(0.f, 0.f);

    // ---- phase 1: acc[r][j] = sum_h B2t[h][pp] * Us[(b0+2r)*128+h][j] ----
    for (int hh = 0; hh < 128; ++hh) {
        float2 w = B2t[hh * 128 + pp];
        #pragma unroll
        for (int r = 0; r < 4; ++r) {
            const float4* up = (const float4*)&Us[(b0 + 2 * r) * 128 + hh][0];
            float4 u01 = up[0], u23 = up[1];
            acc[r][0].x += w.x * u01.x - w.y * u01.y; acc[r][0].y += w.x * u01.y + w.y * u01.x;
            acc[r][1].x += w.x * u01.z - w.y * u01.w; acc[r][1].y += w.x * u01.w + w.y * u01.z;
            acc[r][2].x += w.x * u23.x - w.y * u23.y; acc[r][2].y += w.x * u23.y + w.y * u23.x;
            acc[r][3].x += w.x * u23.z - w.y * u23.w; acc[r][3].y += w.x * u23.w + w.y * u23.z;
        }
    }
    // ---- mid(pp, l) multiply, write Tm ----
    {
        float lr = Lam[pp * 2 + 0], li = Lam[pp * 2 + 1];
        #pragma unroll
        for (int j = 0; j < 4; ++j) {
            float wl = 3.14159265358979f * (float)(l0 + j) / 2048.0f;  // 2*pi*l/4096
            float dr = -lr;
            float di = wl - li;
            float inv = 1.0f / (dr * dr + di * di);
            float mr = dr * inv, mi = -di * inv;
            #pragma unroll
            for (int r = 0; r < 4; ++r) {
                float2 t;
                t.x = acc[r][j].x * mr - acc[r][j].y * mi;
                t.y = acc[r][j].x * mi + acc[r][j].y * mr;
                Tm[(b0 + 2 * r) * 128 + pp][j] = t;
            }
        }
    }
    __syncthreads();   // Tm visible to all

    // ---- phase 2: acc[r][j] = sum_k C2t[k][pp]*Tm[row][j] + D2t[k][pp]*Us[row][j]
    #pragma unroll
    for (int r = 0; r < 4; ++r)
        #pragma unroll
        for (int j = 0; j < 4; ++j) acc[r][j] = make_float2(0.f, 0.f);
    for (int k = 0; k < 128; ++k) {
        float2 c = C2t[k * 128 + pp];
        float2 d = D2t[k * 128 + pp];
        #pragma unroll
        for (int r = 0; r < 4; ++r) {
            const float4* tp = (const float4*)&Tm[(b0 + 2 * r) * 128 + k][0];
            float4 t01 = tp[0], t23 = tp[1];
            const float4* up = (const float4*)&Us[(b0 + 2 * r) * 128 + k][0];
            float4 u01 = up[0], u23 = up[1];
            acc[r][0].x += c.x * t01.x - c.y * t01.y + d.x * u01.x - d.y * u01.y;
            acc[r][0].y += c.x * t01.y + c.y * t01.x + d.x * u01.y + d.y * u01.x;
            acc[r][1].x += c.x * t01.z - c.y * t01.w + d.x * u01.z - d.y * u01.w;
            acc[r][1].y += c.x * t01.w + c.y * t01.z + d.x * u01.w + d.y * u01.z;
            acc[r][2].x += c.x * t23.x - c.y * t23.y + d.x * u23.x - d.y * u23.y;
            acc[r][2].y += c.x * t23.y + c.y * t23.x + d.x * u23.y + d.y * u23.x;
            acc[r][3].x += c.x * t23.z - c.y * t23.w + d.x * u23.z - d.y * u23.w;
            acc[r][3].y += c.x * t23.w + c.y * t23.z + d.x * u23.w + d.y * u23.z;
        }
    }
    __syncthreads();   // all Us/Tm reads complete before overwrite

    #pragma unroll
    for (int r = 0; r < 4; ++r) {
        float4* up = (float4*)&Us[(b0 + 2 * r) * 128 + pp][0];
        up[0] = make_float4(acc[r][0].x, acc[r][0].y, acc[r][1].x, acc[r][1].y);
        up[1] = make_float4(acc[r][2].x, acc[r][2].y, acc[r][3].x, acc[r][3].y);
    }
    __syncthreads();

    for (int i = tid; i < NROWS * TL; i += 256) {
        int r = i >> 2, j = i & (TL - 1);
        int l = l0 + j;
        if (l < LF) Uhat[(size_t)r * LF + l] = Us[r][j];
    }
}

// ---------------------------------------------------------------------------
extern "C" void kernel_launch(void* const* d_in, const int* in_sizes, int n_in,
                              void* d_out, int out_size, void* d_ws, size_t ws_size,
                              hipStream_t stream) {
    const float* u    = (const float*)d_in[0];   // (B,H,L)
    const float* C_ri = (const float*)d_in[1];   // (H,P,2)
    const float* D_ri = (const float*)d_in[2];   // (H,H,2)
    const float* B_ri = (const float*)d_in[3];   // (P,H,2)
    const float* Lam  = (const float*)d_in[4];   // (P,2)
    float* out = (float*)d_out;

    float2* Uhat = (float2*)d_ws;                  // NROWS*LF float2 = 16.0 MiB
    float2* B2t  = Uhat + (size_t)NROWS * LF;
    float2* C2t  = B2t + 128 * 128;
    float2* D2t  = C2t + 128 * 128;
    float2* Em   = D2t + 128 * 128;

    prep_B2t_k<<<64, 256, 0, stream>>>(B_ri, B2t);
    prep_C2t_k<<<64, 256, 0, stream>>>(C_ri, C2t);
    prep_E_k  <<<64, 256, 0, stream>>>(D_ri, Em);
    prep_D2t_k<<<64, 256, 0, stream>>>(Em, D2t);

    rfft_rows_k<<<NROWS, 256, 0, stream>>>(u, Uhat);
    mixfreq_k<<<(LF + TL - 1) / TL, 256, 0, stream>>>(Uhat, B2t, C2t, D2t, Lam);
    irfft_gelu_k<<<NROWS, 256, 0, stream>>>(Uhat, out);
}

// Round 3
// 215.401 us; speedup vs baseline: 2.0000x; 2.0000x over previous
//
#include <hip/hip_runtime.h>
#include <math.h>

#define Bn 8
#define Hn 128
#define Pn 128
#define Ln 4096
#define LF 2049           // Ln/2 + 1
#define NROWS (Bn*Hn)     // 1024
#define NT 32             // frequency columns per mixmm block
#define NTILES 65         // ceil(2049/32) per batch
#define PLSZ 4096         // ushorts per data plane (32 x 128)
#define WPLSZ 16384       // ushorts per weight plane (128 x 128)

typedef __attribute__((ext_vector_type(8))) short short8;
typedef __attribute__((ext_vector_type(4))) float f32x4;

// ---------------------------------------------------------------------------
// bf16 helpers: round-to-nearest-even conversion + hi/lo split
// ---------------------------------------------------------------------------
__device__ __forceinline__ unsigned short bf16_rne(float x) {
    unsigned u = __float_as_uint(x);
    unsigned r = u + 0x7FFFu + ((u >> 16) & 1u);
    return (unsigned short)(r >> 16);
}
__device__ __forceinline__ void bf16_split(float x, unsigned short& hi, unsigned short& lo) {
    hi = bf16_rne(x);
    float fhi = __uint_as_float(((unsigned)hi) << 16);
    lo = bf16_rne(x - fhi);
}

// ---------------------------------------------------------------------------
// prep kernels: fold H-axis FFTs into weights; emit bf16 hi/lo planes in
// MFMA A-operand layout [m][k] row-major 128x128.
// Plane order per matrix: 0 r_hi, 1 i_hi, 2 (-i)_hi, 3 r_lo, 4 i_lo, 5 (-i)_lo
//   W1[p][h] = (B_bar @ F)[p][h]          (stage 1: T = B2 @ U)
//   W2[h][p] = (Finv @ C)[h][p]           (stage 2: C2 @ T)
//   E [a][q] = (D @ F)[a][q]  (fp32 temp)
//   W3[h][q] = (Finv @ E)[h][q]           (stage 2: D2 @ U)
// ---------------------------------------------------------------------------
__device__ __forceinline__ void write6(unsigned short* __restrict__ W, int idx,
                                       float vr, float vi) {
    unsigned short rh, rl, ih, il, nh, nl;
    bf16_split(vr, rh, rl);
    bf16_split(vi, ih, il);
    bf16_split(-vi, nh, nl);
    W[0 * WPLSZ + idx] = rh;
    W[1 * WPLSZ + idx] = ih;
    W[2 * WPLSZ + idx] = nh;
    W[3 * WPLSZ + idx] = rl;
    W[4 * WPLSZ + idx] = il;
    W[5 * WPLSZ + idx] = nl;
}

__global__ void prep_W1_k(const float* __restrict__ B_ri, unsigned short* __restrict__ W1) {
    int idx = blockIdx.x * blockDim.x + threadIdx.x;   // p*128 + h
    int p = idx >> 7, h = idx & 127;
    float sr = 0.f, si = 0.f;
    for (int q = 0; q < 128; ++q) {
        float br = B_ri[(p * 128 + q) * 2 + 0];
        float bi = B_ri[(p * 128 + q) * 2 + 1];
        float ang = -3.14159265358979f * (float)((q * h) & 127) / 64.0f;
        float sw, cw; __sincosf(ang, &sw, &cw);
        sr += br * cw - bi * sw;
        si += br * sw + bi * cw;
    }
    write6(W1, idx, sr, si);
}

__global__ void prep_W2_k(const float* __restrict__ C_ri, unsigned short* __restrict__ W2) {
    int idx = blockIdx.x * blockDim.x + threadIdx.x;   // h*128 + p
    int h = idx >> 7, p = idx & 127;
    float sr = 0.f, si = 0.f;
    for (int h2 = 0; h2 < 128; ++h2) {
        float cr = C_ri[(h2 * 128 + p) * 2 + 0];
        float ci = C_ri[(h2 * 128 + p) * 2 + 1];
        float ang = 3.14159265358979f * (float)((h * h2) & 127) / 64.0f;
        float sw, cw; __sincosf(ang, &sw, &cw);
        sr += cr * cw - ci * sw;
        si += cr * sw + ci * cw;
    }
    write6(W2, idx, sr * (1.0f / 128.0f), si * (1.0f / 128.0f));
}

__global__ void prep_E_k(const float* __restrict__ D_ri, float2* __restrict__ E) {
    int idx = blockIdx.x * blockDim.x + threadIdx.x;   // a*128 + q
    int a = idx >> 7, q = idx & 127;
    float sr = 0.f, si = 0.f;
    for (int c = 0; c < 128; ++c) {
        float dr = D_ri[(a * 128 + c) * 2 + 0];
        float di = D_ri[(a * 128 + c) * 2 + 1];
        float ang = -3.14159265358979f * (float)((c * q) & 127) / 64.0f;
        float sw, cw; __sincosf(ang, &sw, &cw);
        sr += dr * cw - di * sw;
        si += dr * sw + di * cw;
    }
    E[idx] = make_float2(sr, si);
}

__global__ void prep_W3_k(const float2* __restrict__ E, unsigned short* __restrict__ W3) {
    int idx = blockIdx.x * blockDim.x + threadIdx.x;   // h*128 + q
    int h = idx >> 7, q = idx & 127;
    float sr = 0.f, si = 0.f;
    for (int a = 0; a < 128; ++a) {
        float2 e = E[a * 128 + q];
        float ang = 3.14159265358979f * (float)((h * a) & 127) / 64.0f;
        float sw, cw; __sincosf(ang, &sw, &cw);
        sr += e.x * cw - e.y * sw;
        si += e.x * sw + e.y * cw;
    }
    write6(W3, idx, sr * (1.0f / 128.0f), si * (1.0f / 128.0f));
}

// ---------------------------------------------------------------------------
// 4096-pt Stockham radix-4 FFT in LDS (unchanged from round 2 — verified).
// ---------------------------------------------------------------------------
template <int SIGN>
__device__ __forceinline__ void stockham4096_r4(float2* bufA, float2* bufB) {
    const int tid = threadIdx.x;
    float2* src = bufA;
    float2* dst = bufB;
    #pragma unroll
    for (int st = 0; st < 6; ++st) {
        const int ls = 2 * st;
        const int n = 4096 >> ls;
        const int mq = n >> 2;
        const float invn = 1.0f / (float)n;
        #pragma unroll
        for (int r = 0; r < 4; ++r) {
            int k = tid + (r << 8);
            int q = k & ((1 << ls) - 1);
            int p = k >> ls;
            float2 a0 = src[q + ((p         ) << ls)];
            float2 a1 = src[q + ((p +     mq) << ls)];
            float2 a2 = src[q + ((p + 2 * mq) << ls)];
            float2 a3 = src[q + ((p + 3 * mq) << ls)];
            float t0x = a0.x + a2.x, t0y = a0.y + a2.y;
            float t1x = a0.x - a2.x, t1y = a0.y - a2.y;
            float t2x = a1.x + a3.x, t2y = a1.y + a3.y;
            float t3x = a1.x - a3.x, t3y = a1.y - a3.y;
            float B0x = t0x + t2x, B0y = t0y + t2y;
            float B2x = t0x - t2x, B2y = t0y - t2y;
            float B1x = t1x - (float)SIGN * t3y, B1y = t1y + (float)SIGN * t3x;
            float B3x = t1x + (float)SIGN * t3y, B3y = t1y - (float)SIGN * t3x;
            float ang = (float)SIGN * 6.28318530717959f * (float)p * invn;
            float s1, c1; __sincosf(ang, &s1, &c1);
            float c2 = c1 * c1 - s1 * s1, s2 = 2.0f * c1 * s1;
            float c3 = c2 * c1 - s2 * s1, s3 = c2 * s1 + s2 * c1;
            int o = q + (p << (ls + 2));
            dst[o              ] = make_float2(B0x, B0y);
            dst[o + (1 << ls)  ] = make_float2(B1x * c1 - B1y * s1, B1x * s1 + B1y * c1);
            dst[o + (2 << ls)  ] = make_float2(B2x * c2 - B2y * s2, B2x * s2 + B2y * c2);
            dst[o + (3 << ls)  ] = make_float2(B3x * c3 - B3y * s3, B3x * s3 + B3y * c3);
        }
        __syncthreads();
        float2* t = src; src = dst; dst = t;
    }
}

__global__ __launch_bounds__(256) void rfft_rows_k(const float* __restrict__ u,
                                                   float2* __restrict__ Uhat) {
    __shared__ __align__(16) float2 bufA[4096];
    __shared__ __align__(16) float2 bufB[4096];
    const int row = blockIdx.x;
    const int tid = threadIdx.x;
    const float* up = u + (size_t)row * Ln;
    for (int i = tid; i < Ln; i += 256) bufA[i] = make_float2(up[i], 0.f);
    __syncthreads();
    stockham4096_r4<-1>(bufA, bufB);
    float2* op = Uhat + (size_t)row * LF;
    for (int l = tid; l < LF; l += 256) op[l] = bufA[l];
}

__global__ __launch_bounds__(256) void irfft_gelu_k(const float2* __restrict__ Uhat,
                                                    float* __restrict__ out) {
    __shared__ __align__(16) float2 bufA[4096];
    __shared__ __align__(16) float2 bufB[4096];
    const int row = blockIdx.x;
    const int tid = threadIdx.x;
    const float2* wp = Uhat + (size_t)row * LF;
    for (int l = tid; l < LF; l += 256) {
        float2 v = wp[l];
        bufA[l] = v;
        if (l >= 1 && l <= Ln / 2 - 1) bufA[Ln - l] = make_float2(v.x, -v.y);
    }
    __syncthreads();
    stockham4096_r4<1>(bufA, bufB);
    float* op = out + (size_t)row * Ln;
    for (int i = tid; i < Ln; i += 256) {
        float y = bufA[i].x * (1.0f / (float)Ln);
        op[i] = 0.5f * y * (1.0f + erff(y * 0.70710678118655f));
    }
}

// ---------------------------------------------------------------------------
// mixmm: MFMA version of the frequency-domain mixing.
// Per block: one batch b, 32 consecutive bins. Full M=K=128.
//   T = B2 @ U ; T *= mid(p,l) ; W = C2 @ T + D2 @ U ; Uhat tile <- W
// bf16 3-term hi/lo split (A_hi*B_hi + A_lo*B_hi + A_hi*B_lo) for ~fp32 acc.
// Data planes in LDS, layout [n][k] (k contiguous), XOR-swizzled
// k^= (n&7)<<3 for conflict-free ds_read_b128 fragments.
// MFMA 16x16x32 bf16; verified layouts:
//   A[m=lane&15][k=(lane>>4)*8+j], B[k=(lane>>4)*8+j][n=lane&15],
//   C/D: col=lane&15, row=(lane>>4)*4+reg.
// ---------------------------------------------------------------------------
__device__ __forceinline__ f32x4 mfma16(short8 a, short8 b, f32x4 c) {
    return __builtin_amdgcn_mfma_f32_16x16x32_bf16(a, b, c, 0, 0, 0);
}

__device__ __forceinline__ short8 read_frag(const unsigned short* plane, int n, int k) {
    int ksw = k ^ ((n & 7) << 3);
    return *(const short8*)(plane + n * 128 + ksw);
}
__device__ __forceinline__ short8 aread(const unsigned short* W, int pl, int m, int k) {
    return *(const short8*)(W + pl * WPLSZ + m * 128 + k);
}

// 12 MFMAs: complex acc += (A hi/lo planes) * (B hi/lo fragments), 3-term split
__device__ __forceinline__ void cmfma12(const short8 A[6],
                                        short8 brh, short8 bih, short8 brl, short8 bil,
                                        f32x4& aR, f32x4& aI) {
    aR = mfma16(A[0], brh, aR);  aR = mfma16(A[2], bih, aR);   // hi*hi
    aR = mfma16(A[3], brh, aR);  aR = mfma16(A[5], bih, aR);   // lo*hi
    aR = mfma16(A[0], brl, aR);  aR = mfma16(A[2], bil, aR);   // hi*lo
    aI = mfma16(A[0], bih, aI);  aI = mfma16(A[1], brh, aI);
    aI = mfma16(A[3], bih, aI);  aI = mfma16(A[4], brh, aI);
    aI = mfma16(A[0], bil, aI);  aI = mfma16(A[1], brl, aI);
}

__global__ __launch_bounds__(256, 2) void mixmm_k(float2* __restrict__ Uhat,
                                                  const unsigned short* __restrict__ W1,
                                                  const unsigned short* __restrict__ W2,
                                                  const unsigned short* __restrict__ W3,
                                                  const float* __restrict__ Lam) {
    // data planes: 0 r_hi, 1 i_hi, 2 r_lo, 3 i_lo
    __shared__ __align__(16) unsigned short Up[4 * PLSZ];    // 32 KB, U planes
    __shared__ __align__(16) unsigned short TpU[4 * PLSZ];   // 32 KB, T planes / U fp32 stage
    float2* Ustage = (float2*)TpU;                           // [128][32] overlay

    const int tid = threadIdx.x;
    const int b = blockIdx.x / NTILES;
    const int tile = blockIdx.x % NTILES;
    const int l0 = tile * NT;
    const int ncols = (LF - l0) < NT ? (LF - l0) : NT;

    // ---- load U tile (coalesced) into fp32 staging ----
    for (int i = tid; i < 128 * NT; i += 256) {
        int h = i >> 5, n = i & 31;
        float2 v = make_float2(0.f, 0.f);
        if (n < ncols) v = Uhat[(size_t)(b * 128 + h) * LF + l0 + n];
        Ustage[h * NT + n] = v;
    }
    __syncthreads();

    // ---- convert to bf16 hi/lo planes [n][k=h], swizzled ----
    {
        int n = tid & 31, kc = tid >> 5;   // kc: 0..7, owns h = kc*16 .. kc*16+15
        #pragma unroll
        for (int jc = 0; jc < 2; ++jc) {
            short8 rh, ih, rl, il;
            #pragma unroll
            for (int j = 0; j < 8; ++j) {
                int h = kc * 16 + jc * 8 + j;
                float2 v = Ustage[h * NT + n];
                unsigned short a, bb, c, d;
                bf16_split(v.x, a, bb);
                bf16_split(v.y, c, d);
                rh[j] = (short)a; rl[j] = (short)bb;
                ih[j] = (short)c; il[j] = (short)d;
            }
            int k0 = kc * 16 + jc * 8;
            int ksw = k0 ^ ((n & 7) << 3);
            *(short8*)(Up + 0 * PLSZ + n * 128 + ksw) = rh;
            *(short8*)(Up + 1 * PLSZ + n * 128 + ksw) = ih;
            *(short8*)(Up + 2 * PLSZ + n * 128 + ksw) = rl;
            *(short8*)(Up + 3 * PLSZ + n * 128 + ksw) = il;
        }
    }
    __syncthreads();   // Up ready; Ustage fully consumed (TpU free for T)

    const int lane = tid & 63;
    const int w = tid >> 6;          // wave: rows w*32 .. w*32+31
    const int m15 = lane & 15;
    const int quad = lane >> 4;

    f32x4 aR[2][2], aI[2][2];
    #pragma unroll
    for (int s = 0; s < 2; ++s)
        #pragma unroll
        for (int t = 0; t < 2; ++t) { aR[s][t] = (f32x4)0.f; aI[s][t] = (f32x4)0.f; }

    // ---- stage 1: T = B2 @ U ----
    for (int kb = 0; kb < 4; ++kb) {
        int k = kb * 32 + quad * 8;
        short8 brh[2], bih[2], brl[2], bil[2];
        #pragma unroll
        for (int t = 0; t < 2; ++t) {
            int n = t * 16 + m15;
            brh[t] = read_frag(Up + 0 * PLSZ, n, k);
            bih[t] = read_frag(Up + 1 * PLSZ, n, k);
            brl[t] = read_frag(Up + 2 * PLSZ, n, k);
            bil[t] = read_frag(Up + 3 * PLSZ, n, k);
        }
        #pragma unroll
        for (int s = 0; s < 2; ++s) {
            int m = w * 32 + s * 16 + m15;
            short8 A[6];
            #pragma unroll
            for (int pl = 0; pl < 6; ++pl) A[pl] = aread(W1, pl, m, k);
            #pragma unroll
            for (int t = 0; t < 2; ++t)
                cmfma12(A, brh[t], bih[t], brl[t], bil[t], aR[s][t], aI[s][t]);
        }
    }

    // ---- Cauchy scale + write T planes (hi/lo) into TpU ----
    #pragma unroll
    for (int s = 0; s < 2; ++s) {
        #pragma unroll
        for (int reg = 0; reg < 4; ++reg) {
            int p = w * 32 + s * 16 + quad * 4 + reg;
            float2 lamv = ((const float2*)Lam)[p];
            float dr = -lamv.x;
            #pragma unroll
            for (int t = 0; t < 2; ++t) {
                int n = t * 16 + m15;
                int l = l0 + n;
                float di = 3.14159265358979f * (float)l / 2048.0f - lamv.y;
                float inv = 1.0f / (dr * dr + di * di);
                float xr = aR[s][t][reg], xi = aI[s][t][reg];
                float tr = (xr * dr + xi * di) * inv;
                float ti = (xi * dr - xr * di) * inv;
                unsigned short trh, trl, tih, til;
                bf16_split(tr, trh, trl);
                bf16_split(ti, tih, til);
                int off = n * 128 + (p ^ ((n & 7) << 3));
                TpU[0 * PLSZ + off] = trh;
                TpU[1 * PLSZ + off] = tih;
                TpU[2 * PLSZ + off] = trl;
                TpU[3 * PLSZ + off] = til;
            }
        }
    }
    __syncthreads();   // T planes visible

    // ---- stage 2: W = C2 @ T + D2 @ U ----
    #pragma unroll
    for (int s = 0; s < 2; ++s)
        #pragma unroll
        for (int t = 0; t < 2; ++t) { aR[s][t] = (f32x4)0.f; aI[s][t] = (f32x4)0.f; }

    for (int kb = 0; kb < 4; ++kb) {
        int k = kb * 32 + quad * 8;
        short8 trh[2], tih[2], trl[2], til[2];
        short8 urh[2], uih[2], url[2], uil[2];
        #pragma unroll
        for (int t = 0; t < 2; ++t) {
            int n = t * 16 + m15;
            trh[t] = read_frag(TpU + 0 * PLSZ, n, k);
            tih[t] = read_frag(TpU + 1 * PLSZ, n, k);
            trl[t] = read_frag(TpU + 2 * PLSZ, n, k);
            til[t] = read_frag(TpU + 3 * PLSZ, n, k);
            urh[t] = read_frag(Up + 0 * PLSZ, n, k);
            uih[t] = read_frag(Up + 1 * PLSZ, n, k);
            url[t] = read_frag(Up + 2 * PLSZ, n, k);
            uil[t] = read_frag(Up + 3 * PLSZ, n, k);
        }
        #pragma unroll
        for (int s = 0; s < 2; ++s) {
            int m = w * 32 + s * 16 + m15;
            short8 Ac[6], Ad[6];
            #pragma unroll
            for (int pl = 0; pl < 6; ++pl) { Ac[pl] = aread(W2, pl, m, k); Ad[pl] = aread(W3, pl, m, k); }
            #pragma unroll
            for (int t = 0; t < 2; ++t) {
                cmfma12(Ac, trh[t], tih[t], trl[t], til[t], aR[s][t], aI[s][t]);
                cmfma12(Ad, urh[t], uih[t], url[t], uil[t], aR[s][t], aI[s][t]);
            }
        }
    }

    // ---- write W back to Uhat (in-place, block-disjoint tiles) ----
    #pragma unroll
    for (int s = 0; s < 2; ++s) {
        #pragma unroll
        for (int t = 0; t < 2; ++t) {
            int n = t * 16 + m15;
            if (n < ncols) {
                #pragma unroll
                for (int reg = 0; reg < 4; ++reg) {
                    int m = w * 32 + s * 16 + quad * 4 + reg;
                    Uhat[(size_t)(b * 128 + m) * LF + l0 + n] =
                        make_float2(aR[s][t][reg], aI[s][t][reg]);
                }
            }
        }
    }
}

// ---------------------------------------------------------------------------
extern "C" void kernel_launch(void* const* d_in, const int* in_sizes, int n_in,
                              void* d_out, int out_size, void* d_ws, size_t ws_size,
                              hipStream_t stream) {
    const float* u    = (const float*)d_in[0];   // (B,H,L)
    const float* C_ri = (const float*)d_in[1];   // (H,P,2)
    const float* D_ri = (const float*)d_in[2];   // (H,H,2)
    const float* B_ri = (const float*)d_in[3];   // (P,H,2)
    const float* Lam  = (const float*)d_in[4];   // (P,2)
    float* out = (float*)d_out;

    float2* Uhat = (float2*)d_ws;                          // 1024*2049 float2 = 16 MiB
    unsigned short* W1 = (unsigned short*)(Uhat + (size_t)NROWS * LF);
    unsigned short* W2 = W1 + 6 * WPLSZ;
    unsigned short* W3 = W2 + 6 * WPLSZ;
    float2* Em = (float2*)(W3 + 6 * WPLSZ);

    prep_W1_k<<<64, 256, 0, stream>>>(B_ri, W1);
    prep_W2_k<<<64, 256, 0, stream>>>(C_ri, W2);
    prep_E_k <<<64, 256, 0, stream>>>(D_ri, Em);
    prep_W3_k<<<64, 256, 0, stream>>>(Em, W3);

    rfft_rows_k<<<NROWS, 256, 0, stream>>>(u, Uhat);
    mixmm_k<<<Bn * NTILES, 256, 0, stream>>>(Uhat, W1, W2, W3, Lam);
    irfft_gelu_k<<<NROWS, 256, 0, stream>>>(Uhat, out);
}